// Round 13
// baseline (233.947 us; speedup 1.0000x reference)
//
#include <hip/hip_runtime.h>
#include <hip/hip_bf16.h>

// Problem constants (reference: B=2048, N_BINS=200, D=128, G=100)
#define NB    200
#define BSZ   2048
#define DD    128
#define GG    100
#define WROWS 112                 // gene rows padded in the d_ws image
#define ROWB  256                 // bytes per LDS W row (128 bf16)
#define WIMG  (WROWS * ROWB)      // 28672 B per-bin W image in d_ws
#define WLDS  (GG * ROWB)         // 25600 B staged per LDS buffer (100 real rows)
#define NTILE (NB * 16)           // 3200 (mtile fastest: tile = n*16 + mtile)
#define NBLK  512                 // grid size == tile stride

typedef __attribute__((ext_vector_type(8))) short  short8;  // 8 bf16 (MFMA A/B frag)
typedef __attribute__((ext_vector_type(4))) float  f32x4;   // MFMA C/D frag
typedef __attribute__((ext_vector_type(4))) int    i32x4;   // 16B chunk

// round-to-nearest-even f32 -> bf16, two at a time packed into a dword
__device__ __forceinline__ unsigned f2bf_pack(float lo, float hi) {
    unsigned ulo = __builtin_bit_cast(unsigned, lo);
    ulo += 0x7FFFu + ((ulo >> 16) & 1u);
    unsigned uhi = __builtin_bit_cast(unsigned, hi);
    uhi += 0x7FFFu + ((uhi >> 16) & 1u);
    return (ulo >> 16) | (uhi & 0xFFFF0000u);
}

__device__ __forceinline__ void gload_lds16(const void* g, void* l) {
    __builtin_amdgcn_global_load_lds(
        (const __attribute__((address_space(1))) unsigned int*)g,
        (__attribute__((address_space(3))) unsigned int*)l, 16, 0, 0);
}

// Wave-level LDS drain (scratch is wave-private): lgkmcnt(0) only.
#define WAIT_LGKM0() do { asm volatile("" ::: "memory");     \
                          __builtin_amdgcn_s_waitcnt(0xC07F);\
                          __builtin_amdgcn_sched_barrier(0); \
                          __builtin_amdgcn_wave_barrier();   \
                          asm volatile("" ::: "memory"); } while (0)

// Cross-wave barrier WITHOUT vmcnt drain: prefetch loads stay in flight.
#define BARRIER_LGKM() do { asm volatile("" ::: "memory");      \
                            __builtin_amdgcn_s_waitcnt(0xC07F); \
                            __builtin_amdgcn_s_barrier();       \
                            __builtin_amdgcn_sched_barrier(0);  \
                            asm volatile("" ::: "memory"); } while (0)

// Iteration-end barrier: full drain (r6/r12 proven; r11's counted variant
// regressed — do not re-bundle).
#define BARRIER_VM0() do { asm volatile("s_waitcnt vmcnt(0) lgkmcnt(0)" ::: "memory"); \
                           __builtin_amdgcn_s_barrier();        \
                           __builtin_amdgcn_sched_barrier(0);   \
                           asm volatile("" ::: "memory"); } while (0)

// ---------------------------------------------------------------------------
// Pre-pass: W f32 [NB][GG][DD] -> bf16 swizzled per-bin images in d_ws.
// byte off = row*256 + ((granule*16) ^ ((row&7)<<4)), rows >= GG zeroed.
// ---------------------------------------------------------------------------
__global__ __launch_bounds__(256) void wconv_kernel(
    const float* __restrict__ W, unsigned char* __restrict__ ws)
{
    const int gidx = blockIdx.x * 256 + threadIdx.x;
    if (gidx >= NB * WROWS * 16) return;
    const int gr  = gidx & 15;
    const int row = (gidx >> 4) % WROWS;
    const int n   = gidx / (WROWS * 16);
    i32x4 pack = (i32x4){0, 0, 0, 0};
    if (row < GG) {
        const float* src = W + ((size_t)n * GG + row) * DD + gr * 8;
        const f32x4 a = *reinterpret_cast<const f32x4*>(src);
        const f32x4 b = *reinterpret_cast<const f32x4*>(src + 4);
        pack.x = (int)f2bf_pack(a[0], a[1]);
        pack.y = (int)f2bf_pack(a[2], a[3]);
        pack.z = (int)f2bf_pack(b[0], b[1]);
        pack.w = (int)f2bf_pack(b[2], b[3]);
    }
    const int off = row * ROWB + ((gr * 16) ^ ((row & 7) << 4));
    *reinterpret_cast<i32x4*>(ws + (size_t)n * WIMG + off) = pack;
}

// ---------------------------------------------------------------------------
// Pipelined main kernel helpers (r12 structure; staging cut to 100 rows)
// ---------------------------------------------------------------------------
// Stage the 100 real rows (25600 B) of bin n's image: 25 wave-chunks of 1024 B.
__device__ __forceinline__ void stage_tile(char* buf, const unsigned char* WS,
                                           int n, int lane, int wid) {
    const unsigned char* src = WS + (size_t)n * WIMG;
    #pragma unroll
    for (int i = 0; i < 6; ++i) {
        const int c = i * 4 + wid;                    // chunks 0..23
        gload_lds16(src + c * 1024 + lane * 16, buf + c * 1024);
    }
    if (wid == 0)                                     // chunk 24 (rows 96..99)
        gload_lds16(src + 24 * 1024 + lane * 16, buf + 24 * 1024);
}

__device__ __forceinline__ void load_x(f32x4 (&raw)[2][4][2], const float* X,
                                       int tile, int wid, int l15, int lhi) {
    const int n = tile >> 4;
    const int rowbase = (tile & 15) * 128 + wid * 32;
    #pragma unroll
    for (int rf = 0; rf < 2; ++rf) {
        const float* xrow = X + ((size_t)(rowbase + rf * 16 + l15) * NB + n) * DD + lhi * 8;
        #pragma unroll
        for (int ks = 0; ks < 4; ++ks) {
            raw[rf][ks][0] = *reinterpret_cast<const f32x4*>(xrow + ks * 32);
            raw[rf][ks][1] = *reinterpret_cast<const f32x4*>(xrow + ks * 32 + 4);
        }
    }
}

__device__ __forceinline__ void conv_x(const f32x4 (&raw)[2][4][2],
                                       short8 (&areg)[2][4]) {
    #pragma unroll
    for (int rf = 0; rf < 2; ++rf)
        #pragma unroll
        for (int ks = 0; ks < 4; ++ks) {
            const f32x4 a = raw[rf][ks][0];
            const f32x4 b = raw[rf][ks][1];
            i32x4 pk;
            pk.x = (int)f2bf_pack(a[0], a[1]);
            pk.y = (int)f2bf_pack(a[2], a[3]);
            pk.z = (int)f2bf_pack(b[0], b[1]);
            pk.w = (int)f2bf_pack(b[2], b[3]);
            areg[rf][ks] = __builtin_bit_cast(short8, pk);
        }
}

// One tile: prefetch next (W->bufN async, X->raw), MFMA current from bufC,
// epilogue through bufC scratch, convert raw->aregN, end barrier.
__device__ __forceinline__ bool tile_body(int tile,
    const float* __restrict__ X, const float* __restrict__ Bias,
    float* __restrict__ Out, const unsigned char* __restrict__ WS,
    char* bufC, char* bufN,
    short8 (&aregC)[2][4], short8 (&aregN)[2][4], f32x4 (&raw)[2][4][2],
    int lane, int wid, int l15, int lhi)
{
    const int n       = tile >> 4;
    const int rowbase = (tile & 15) * 128 + wid * 32;
    const int tn      = tile + NBLK;
    const bool hasnext = (tn < NTILE);

    // 1. issue next-tile prefetch FIRST (hides HBM latency under this tile)
    if (hasnext) {
        stage_tile(bufN, WS, tn >> 4, lane, wid);
        load_x(raw, X, tn, wid, l15, lhi);
    }
    float bias[7];
    #pragma unroll
    for (int cf = 0; cf < 7; ++cf) {
        const int g = cf * 16 + l15;
        bias[cf] = (g < GG) ? Bias[n * GG + g] : 0.0f;
    }

    // 2. MFMA: 2 row-frags x 7 col-frags x 4 k-steps from bufC
    f32x4 acc[2][7];
    #pragma unroll
    for (int rf = 0; rf < 2; ++rf)
        #pragma unroll
        for (int cf = 0; cf < 7; ++cf)
            acc[rf][cf] = (f32x4){0.f, 0.f, 0.f, 0.f};

    #pragma unroll
    for (int cf = 0; cf < 7; ++cf) {
        const int g = cf * 16 + l15;
        const int r = (g < GG) ? g : (GG - 1);   // rows >=100 not staged; masked at store
        const int rowb = r * ROWB;
        const int swz  = (r & 7) << 4;
        #pragma unroll
        for (int ks = 0; ks < 4; ++ks) {
            const int off = rowb + (((lhi * 16) + ks * 64) ^ swz);
            const i32x4 braw = *reinterpret_cast<const i32x4*>(bufC + off);  // ds_read_b128
            const short8 bfrag = __builtin_bit_cast(short8, braw);
            acc[0][cf] = __builtin_amdgcn_mfma_f32_16x16x32_bf16(aregC[0][ks], bfrag, acc[0][cf], 0, 0, 0);
            acc[1][cf] = __builtin_amdgcn_mfma_f32_16x16x32_bf16(aregC[1][ks], bfrag, acc[1][cf], 0, 0, 0);
        }
    }

    // 3. all waves done reading bufC (raw barrier: prefetch stays in flight)
    BARRIER_LGKM();

    // 4. epilogue: wave-private transpose in bufC scratch -> contiguous NT stores
    //    (4 waves x 6400 B == WLDS exactly)
    float* lds_f = reinterpret_cast<float*>(bufC + wid * 6400);
    #pragma unroll
    for (int rf = 0; rf < 2; ++rf) {
        #pragma unroll
        for (int cf = 0; cf < 7; ++cf) {
            const int g = cf * 16 + l15;
            if (g < GG) {
                #pragma unroll
                for (int j = 0; j < 4; ++j)
                    lds_f[(lhi * 4 + j) * GG + g] = acc[rf][cf][j] + bias[cf];
            }
        }
        WAIT_LGKM0();
        const char* rgn = bufC + wid * 6400;
        char* dst = (char*)(Out + ((size_t)n * BSZ + rowbase + rf * 16) * GG);
        #pragma unroll
        for (int it = 0; it < 7; ++it) {
            const int c = it * 64 + lane;         // 16B-chunk index, 400 total
            if (c < 400) {
                const i32x4 v = *reinterpret_cast<const i32x4*>(rgn + c * 16);
                __builtin_nontemporal_store(v, reinterpret_cast<i32x4*>(dst + c * 16));
            }
        }
        WAIT_LGKM0();   // scratch reads done before rf=1 overwrites
    }

    // 5. convert next tile's X (compiler inserts the counted vmcnt for raw)
    if (hasnext) conv_x(raw, aregN);

    // 6. iteration end: next-tile staging complete for all waves
    BARRIER_VM0();
    return hasnext;
}

__global__ __launch_bounds__(256, 3) void mtl_heads_pipe(
    const float* __restrict__ X, const float* __restrict__ Bias,
    const unsigned char* __restrict__ WS, float* __restrict__ Out)
{
    const int tid  = threadIdx.x;
    const int lane = tid & 63;
    const int wid  = tid >> 6;
    const int l15  = lane & 15;
    const int lhi  = lane >> 4;

    __shared__ __align__(16) char smem[2 * WLDS];   // 51200 B -> 3 blocks/CU
    char* bufA = smem;
    char* bufB = smem + WLDS;

    short8 aregA[2][4], aregB[2][4];
    f32x4  raw[2][4][2];

    // XCD-aware swizzle (T1, r12-proven): XCD k's 64 blocks cover 64
    // CONSECUTIVE tiles (= 4 bins) per pipeline step -> X-slab + W images
    // fit its private 4 MB L2. Bijective on [0,512).
    int t = ((blockIdx.x & 7) << 6) + (blockIdx.x >> 3);

    // prologue: stage tile t0 into bufA, load its X, drain, convert
    stage_tile(bufA, WS, t >> 4, lane, wid);
    load_x(raw, X, t, wid, l15, lhi);
    BARRIER_VM0();
    conv_x(raw, aregA);

    // ping-pong main loop (tile count uniform across waves -> barriers lockstep)
    for (;;) {
        if (!tile_body(t, X, Bias, Out, WS, bufA, bufB, aregA, aregB, raw,
                       lane, wid, l15, lhi)) break;
        t += NBLK;
        if (!tile_body(t, X, Bias, Out, WS, bufB, bufA, aregB, aregA, raw,
                       lane, wid, l15, lhi)) break;
        t += NBLK;
    }
}

// ---------------------------------------------------------------------------
// Fallback (no workspace): single-tile kernel, in-kernel W convert.
// ---------------------------------------------------------------------------
__global__ __launch_bounds__(256, 4) void mtl_heads_fallback(
    const float* __restrict__ X, const float* __restrict__ W,
    const float* __restrict__ Bias, float* __restrict__ Out)
{
    const int n     = blockIdx.y;
    const int mtile = blockIdx.x;
    const int tid   = threadIdx.x;
    const int lane  = tid & 63;
    const int wid   = tid >> 6;
    const int l15   = lane & 15;
    const int lhi   = lane >> 4;

    __shared__ __align__(16) char smem[WIMG];

    {
        const int rsub = tid >> 4;
        const int k0   = (tid & 15) * 8;
        #pragma unroll
        for (int it = 0; it < 7; ++it) {
            const int row = it * 16 + rsub;
            i32x4 pack = (i32x4){0, 0, 0, 0};
            if (row < GG) {
                const float* s = W + ((size_t)n * GG + row) * DD + k0;
                const f32x4 a = *reinterpret_cast<const f32x4*>(s);
                const f32x4 b = *reinterpret_cast<const f32x4*>(s + 4);
                pack.x = (int)f2bf_pack(a[0], a[1]);
                pack.y = (int)f2bf_pack(a[2], a[3]);
                pack.z = (int)f2bf_pack(b[0], b[1]);
                pack.w = (int)f2bf_pack(b[2], b[3]);
            }
            const int off = row * ROWB + ((k0 * 2) ^ ((row & 7) << 4));
            *reinterpret_cast<i32x4*>(smem + off) = pack;
        }
    }

    const int rowbase = mtile * 128 + wid * 32;
    f32x4 raw[2][4][2];
    load_x(raw, X, n * 16 + mtile, wid, l15, lhi);
    float bias[7];
    #pragma unroll
    for (int cf = 0; cf < 7; ++cf) {
        const int g = cf * 16 + l15;
        bias[cf] = (g < GG) ? Bias[n * GG + g] : 0.0f;
    }
    short8 areg[2][4];
    conv_x(raw, areg);

    __syncthreads();

    f32x4 acc[2][7];
    #pragma unroll
    for (int rf = 0; rf < 2; ++rf)
        #pragma unroll
        for (int cf = 0; cf < 7; ++cf)
            acc[rf][cf] = (f32x4){0.f, 0.f, 0.f, 0.f};

    #pragma unroll
    for (int cf = 0; cf < 7; ++cf) {
        const int g    = cf * 16 + l15;
        const int rowb = g * ROWB;
        const int swz  = (g & 7) << 4;
        #pragma unroll
        for (int ks = 0; ks < 4; ++ks) {
            const int off = rowb + (((lhi * 16) + ks * 64) ^ swz);
            const i32x4 braw = *reinterpret_cast<const i32x4*>(smem + off);
            const short8 bfrag = __builtin_bit_cast(short8, braw);
            acc[0][cf] = __builtin_amdgcn_mfma_f32_16x16x32_bf16(areg[0][ks], bfrag, acc[0][cf], 0, 0, 0);
            acc[1][cf] = __builtin_amdgcn_mfma_f32_16x16x32_bf16(areg[1][ks], bfrag, acc[1][cf], 0, 0, 0);
        }
    }

    __syncthreads();

    float* lds_f = reinterpret_cast<float*>(smem + wid * 6400);
    #pragma unroll
    for (int rf = 0; rf < 2; ++rf) {
        #pragma unroll
        for (int cf = 0; cf < 7; ++cf) {
            const int g = cf * 16 + l15;
            if (g < GG) {
                #pragma unroll
                for (int j = 0; j < 4; ++j)
                    lds_f[(lhi * 4 + j) * GG + g] = acc[rf][cf][j] + bias[cf];
            }
        }
        WAIT_LGKM0();
        const char* rgn = smem + wid * 6400;
        char* dst = (char*)(Out + ((size_t)n * BSZ + rowbase + rf * 16) * GG);
        #pragma unroll
        for (int it = 0; it < 7; ++it) {
            const int c = it * 64 + lane;
            if (c < 400) {
                const i32x4 v = *reinterpret_cast<const i32x4*>(rgn + c * 16);
                *reinterpret_cast<i32x4*>(dst + c * 16) = v;
            }
        }
        WAIT_LGKM0();
    }
}

extern "C" void kernel_launch(void* const* d_in, const int* in_sizes, int n_in,
                              void* d_out, int out_size, void* d_ws, size_t ws_size,
                              hipStream_t stream) {
    (void)in_sizes; (void)n_in; (void)out_size;
    const float* X    = (const float*)d_in[0];
    const float* W    = (const float*)d_in[1];
    const float* Bias = (const float*)d_in[2];
    float* Out        = (float*)d_out;
    const size_t wsneed = (size_t)NB * WIMG;   // 5,734,400 B
    if (ws_size >= wsneed) {
        wconv_kernel<<<(NB * WROWS * 16 + 255) / 256, 256, 0, stream>>>(W, (unsigned char*)d_ws);
        mtl_heads_pipe<<<dim3(NBLK), 256, 0, stream>>>(X, Bias, (const unsigned char*)d_ws, Out);
    } else {
        mtl_heads_fallback<<<dim3(16, NB), 256, 0, stream>>>(X, W, Bias, Out);
    }
}

// Round 14
// 107.778 us; speedup vs baseline: 2.1706x; 2.1706x over previous
//
#include <hip/hip_runtime.h>
#include <hip/hip_bf16.h>

// Problem constants (reference: B=2048, N_BINS=200, D=128, G=100)
#define NB    200
#define BSZ   2048
#define DD    128
#define GG    100
#define WROWS 112                 // gene rows padded in the d_ws image
#define ROWB  256                 // bytes per LDS W row (128 bf16)
#define WIMG  (WROWS * ROWB)      // 28672 B per-bin W image in d_ws
#define WLDS  (GG * ROWB)         // 25600 B staged per LDS buffer (100 real rows)
#define NTILE (NB * 16)           // 3200 (mtile fastest: tile = n*16 + mtile)
#define NBLK  768                 // grid size == tile stride; 3 blocks/CU (LDS-limited)

typedef __attribute__((ext_vector_type(8))) short  short8;  // 8 bf16 (MFMA A/B frag)
typedef __attribute__((ext_vector_type(4))) float  f32x4;   // MFMA C/D frag
typedef __attribute__((ext_vector_type(4))) int    i32x4;   // 16B chunk

// round-to-nearest-even f32 -> bf16, two at a time packed into a dword
__device__ __forceinline__ unsigned f2bf_pack(float lo, float hi) {
    unsigned ulo = __builtin_bit_cast(unsigned, lo);
    ulo += 0x7FFFu + ((ulo >> 16) & 1u);
    unsigned uhi = __builtin_bit_cast(unsigned, hi);
    uhi += 0x7FFFu + ((uhi >> 16) & 1u);
    return (ulo >> 16) | (uhi & 0xFFFF0000u);
}

__device__ __forceinline__ void gload_lds16(const void* g, void* l) {
    __builtin_amdgcn_global_load_lds(
        (const __attribute__((address_space(1))) unsigned int*)g,
        (__attribute__((address_space(3))) unsigned int*)l, 16, 0, 0);
}

// Wave-level LDS drain (scratch is wave-private): lgkmcnt(0) only.
#define WAIT_LGKM0() do { asm volatile("" ::: "memory");     \
                          __builtin_amdgcn_s_waitcnt(0xC07F);\
                          __builtin_amdgcn_sched_barrier(0); \
                          __builtin_amdgcn_wave_barrier();   \
                          asm volatile("" ::: "memory"); } while (0)

// Cross-wave barrier WITHOUT vmcnt drain: prefetch loads stay in flight.
#define BARRIER_LGKM() do { asm volatile("" ::: "memory");      \
                            __builtin_amdgcn_s_waitcnt(0xC07F); \
                            __builtin_amdgcn_s_barrier();       \
                            __builtin_amdgcn_sched_barrier(0);  \
                            asm volatile("" ::: "memory"); } while (0)

// Iteration-end barrier: full drain (r6/r12 proven).
#define BARRIER_VM0() do { asm volatile("s_waitcnt vmcnt(0) lgkmcnt(0)" ::: "memory"); \
                           __builtin_amdgcn_s_barrier();        \
                           __builtin_amdgcn_sched_barrier(0);   \
                           asm volatile("" ::: "memory"); } while (0)

// NOTE (r11/r13 lesson): __launch_bounds__(256,3) makes the scheduler chase a
// high-occupancy register budget -> squeezes to 84 VGPR by SPILLING the X
// prefetch to scratch -> +250 MB VMEM traffic, 2-3x slowdown. Keep (256,2):
// compiler settles at 128 VGPR, no spills; extra residency comes from LDS.

// ---------------------------------------------------------------------------
// Pre-pass: W f32 [NB][GG][DD] -> bf16 swizzled per-bin images in d_ws.
// byte off = row*256 + ((granule*16) ^ ((row&7)<<4)), rows >= GG zeroed.
// ---------------------------------------------------------------------------
__global__ __launch_bounds__(256) void wconv_kernel(
    const float* __restrict__ W, unsigned char* __restrict__ ws)
{
    const int gidx = blockIdx.x * 256 + threadIdx.x;
    if (gidx >= NB * WROWS * 16) return;
    const int gr  = gidx & 15;
    const int row = (gidx >> 4) % WROWS;
    const int n   = gidx / (WROWS * 16);
    i32x4 pack = (i32x4){0, 0, 0, 0};
    if (row < GG) {
        const float* src = W + ((size_t)n * GG + row) * DD + gr * 8;
        const f32x4 a = *reinterpret_cast<const f32x4*>(src);
        const f32x4 b = *reinterpret_cast<const f32x4*>(src + 4);
        pack.x = (int)f2bf_pack(a[0], a[1]);
        pack.y = (int)f2bf_pack(a[2], a[3]);
        pack.z = (int)f2bf_pack(b[0], b[1]);
        pack.w = (int)f2bf_pack(b[2], b[3]);
    }
    const int off = row * ROWB + ((gr * 16) ^ ((row & 7) << 4));
    *reinterpret_cast<i32x4*>(ws + (size_t)n * WIMG + off) = pack;
}

// ---------------------------------------------------------------------------
// Pipelined main kernel helpers
// ---------------------------------------------------------------------------
// Stage the 100 real rows (25600 B) of bin n's image: 25 wave-chunks of 1024 B.
__device__ __forceinline__ void stage_tile(char* buf, const unsigned char* WS,
                                           int n, int lane, int wid) {
    const unsigned char* src = WS + (size_t)n * WIMG;
    #pragma unroll
    for (int i = 0; i < 6; ++i) {
        const int c = i * 4 + wid;                    // chunks 0..23
        gload_lds16(src + c * 1024 + lane * 16, buf + c * 1024);
    }
    if (wid == 0)                                     // chunk 24 (rows 96..99)
        gload_lds16(src + 24 * 1024 + lane * 16, buf + 24 * 1024);
}

__device__ __forceinline__ void load_x(f32x4 (&raw)[2][4][2], const float* X,
                                       int tile, int wid, int l15, int lhi) {
    const int n = tile >> 4;
    const int rowbase = (tile & 15) * 128 + wid * 32;
    #pragma unroll
    for (int rf = 0; rf < 2; ++rf) {
        const float* xrow = X + ((size_t)(rowbase + rf * 16 + l15) * NB + n) * DD + lhi * 8;
        #pragma unroll
        for (int ks = 0; ks < 4; ++ks) {
            raw[rf][ks][0] = *reinterpret_cast<const f32x4*>(xrow + ks * 32);
            raw[rf][ks][1] = *reinterpret_cast<const f32x4*>(xrow + ks * 32 + 4);
        }
    }
}

__device__ __forceinline__ void conv_x(const f32x4 (&raw)[2][4][2],
                                       short8 (&areg)[2][4]) {
    #pragma unroll
    for (int rf = 0; rf < 2; ++rf)
        #pragma unroll
        for (int ks = 0; ks < 4; ++ks) {
            const f32x4 a = raw[rf][ks][0];
            const f32x4 b = raw[rf][ks][1];
            i32x4 pk;
            pk.x = (int)f2bf_pack(a[0], a[1]);
            pk.y = (int)f2bf_pack(a[2], a[3]);
            pk.z = (int)f2bf_pack(b[0], b[1]);
            pk.w = (int)f2bf_pack(b[2], b[3]);
            areg[rf][ks] = __builtin_bit_cast(short8, pk);
        }
}

// One tile: prefetch next (W->bufN async, X->raw), MFMA current from bufC,
// epilogue through bufC scratch, convert raw->aregN, end barrier.
__device__ __forceinline__ bool tile_body(int tile,
    const float* __restrict__ X, const float* __restrict__ Bias,
    float* __restrict__ Out, const unsigned char* __restrict__ WS,
    char* bufC, char* bufN,
    short8 (&aregC)[2][4], short8 (&aregN)[2][4], f32x4 (&raw)[2][4][2],
    int lane, int wid, int l15, int lhi)
{
    const int n       = tile >> 4;
    const int rowbase = (tile & 15) * 128 + wid * 32;
    const int tn      = tile + NBLK;
    const bool hasnext = (tn < NTILE);

    // 1. issue next-tile prefetch FIRST (hides HBM latency under this tile)
    if (hasnext) {
        stage_tile(bufN, WS, tn >> 4, lane, wid);
        load_x(raw, X, tn, wid, l15, lhi);
    }
    float bias[7];
    #pragma unroll
    for (int cf = 0; cf < 7; ++cf) {
        const int g = cf * 16 + l15;
        bias[cf] = (g < GG) ? Bias[n * GG + g] : 0.0f;
    }

    // 2. MFMA: 2 row-frags x 7 col-frags x 4 k-steps from bufC
    f32x4 acc[2][7];
    #pragma unroll
    for (int rf = 0; rf < 2; ++rf)
        #pragma unroll
        for (int cf = 0; cf < 7; ++cf)
            acc[rf][cf] = (f32x4){0.f, 0.f, 0.f, 0.f};

    #pragma unroll
    for (int cf = 0; cf < 7; ++cf) {
        const int g = cf * 16 + l15;
        const int r = (g < GG) ? g : (GG - 1);   // rows >=100 not staged; masked at store
        const int rowb = r * ROWB;
        const int swz  = (r & 7) << 4;
        #pragma unroll
        for (int ks = 0; ks < 4; ++ks) {
            const int off = rowb + (((lhi * 16) + ks * 64) ^ swz);
            const i32x4 braw = *reinterpret_cast<const i32x4*>(bufC + off);  // ds_read_b128
            const short8 bfrag = __builtin_bit_cast(short8, braw);
            acc[0][cf] = __builtin_amdgcn_mfma_f32_16x16x32_bf16(aregC[0][ks], bfrag, acc[0][cf], 0, 0, 0);
            acc[1][cf] = __builtin_amdgcn_mfma_f32_16x16x32_bf16(aregC[1][ks], bfrag, acc[1][cf], 0, 0, 0);
        }
    }

    // 3. all waves done reading bufC (raw barrier: prefetch stays in flight)
    BARRIER_LGKM();

    // 4. epilogue: wave-private transpose in bufC scratch -> contiguous NT stores
    //    (4 waves x 6400 B == WLDS exactly)
    float* lds_f = reinterpret_cast<float*>(bufC + wid * 6400);
    #pragma unroll
    for (int rf = 0; rf < 2; ++rf) {
        #pragma unroll
        for (int cf = 0; cf < 7; ++cf) {
            const int g = cf * 16 + l15;
            if (g < GG) {
                #pragma unroll
                for (int j = 0; j < 4; ++j)
                    lds_f[(lhi * 4 + j) * GG + g] = acc[rf][cf][j] + bias[cf];
            }
        }
        WAIT_LGKM0();
        const char* rgn = bufC + wid * 6400;
        char* dst = (char*)(Out + ((size_t)n * BSZ + rowbase + rf * 16) * GG);
        #pragma unroll
        for (int it = 0; it < 7; ++it) {
            const int c = it * 64 + lane;         // 16B-chunk index, 400 total
            if (c < 400) {
                const i32x4 v = *reinterpret_cast<const i32x4*>(rgn + c * 16);
                __builtin_nontemporal_store(v, reinterpret_cast<i32x4*>(dst + c * 16));
            }
        }
        WAIT_LGKM0();   // scratch reads done before rf=1 overwrites
    }

    // 5. convert next tile's X (compiler inserts the counted vmcnt for raw)
    if (hasnext) conv_x(raw, aregN);

    // 6. iteration end: next-tile staging complete for all waves
    BARRIER_VM0();
    return hasnext;
}

__global__ __launch_bounds__(256, 2) void mtl_heads_pipe(
    const float* __restrict__ X, const float* __restrict__ Bias,
    const unsigned char* __restrict__ WS, float* __restrict__ Out)
{
    const int tid  = threadIdx.x;
    const int lane = tid & 63;
    const int wid  = tid >> 6;
    const int l15  = lane & 15;
    const int lhi  = lane >> 4;

    __shared__ __align__(16) char smem[2 * WLDS];   // 51200 B -> 3 blocks/CU (LDS limit)
    char* bufA = smem;
    char* bufB = smem + WLDS;

    short8 aregA[2][4], aregB[2][4];
    f32x4  raw[2][4][2];

    // XCD-aware swizzle (T1, r12-proven): XCD k's 96 blocks cover 96
    // CONSECUTIVE tiles (= 6 bins) per pipeline step. Bijective on [0,768).
    int t = (blockIdx.x & 7) * 96 + (blockIdx.x >> 3);

    // prologue: stage tile t0 into bufA, load its X, drain, convert
    stage_tile(bufA, WS, t >> 4, lane, wid);
    load_x(raw, X, t, wid, l15, lhi);
    BARRIER_VM0();
    conv_x(raw, aregA);

    // ping-pong main loop (tile count uniform across waves -> barriers lockstep)
    for (;;) {
        if (!tile_body(t, X, Bias, Out, WS, bufA, bufB, aregA, aregB, raw,
                       lane, wid, l15, lhi)) break;
        t += NBLK;
        if (!tile_body(t, X, Bias, Out, WS, bufB, bufA, aregB, aregA, raw,
                       lane, wid, l15, lhi)) break;
        t += NBLK;
    }
}

// ---------------------------------------------------------------------------
// Fallback (no workspace): single-tile kernel, in-kernel W convert.
// ---------------------------------------------------------------------------
__global__ __launch_bounds__(256, 4) void mtl_heads_fallback(
    const float* __restrict__ X, const float* __restrict__ W,
    const float* __restrict__ Bias, float* __restrict__ Out)
{
    const int n     = blockIdx.y;
    const int mtile = blockIdx.x;
    const int tid   = threadIdx.x;
    const int lane  = tid & 63;
    const int wid   = tid >> 6;
    const int l15   = lane & 15;
    const int lhi   = lane >> 4;

    __shared__ __align__(16) char smem[WIMG];

    {
        const int rsub = tid >> 4;
        const int k0   = (tid & 15) * 8;
        #pragma unroll
        for (int it = 0; it < 7; ++it) {
            const int row = it * 16 + rsub;
            i32x4 pack = (i32x4){0, 0, 0, 0};
            if (row < GG) {
                const float* s = W + ((size_t)n * GG + row) * DD + k0;
                const f32x4 a = *reinterpret_cast<const f32x4*>(s);
                const f32x4 b = *reinterpret_cast<const f32x4*>(s + 4);
                pack.x = (int)f2bf_pack(a[0], a[1]);
                pack.y = (int)f2bf_pack(a[2], a[3]);
                pack.z = (int)f2bf_pack(b[0], b[1]);
                pack.w = (int)f2bf_pack(b[2], b[3]);
            }
            const int off = row * ROWB + ((k0 * 2) ^ ((row & 7) << 4));
            *reinterpret_cast<i32x4*>(smem + off) = pack;
        }
    }

    const int rowbase = mtile * 128 + wid * 32;
    f32x4 raw[2][4][2];
    load_x(raw, X, n * 16 + mtile, wid, l15, lhi);
    float bias[7];
    #pragma unroll
    for (int cf = 0; cf < 7; ++cf) {
        const int g = cf * 16 + l15;
        bias[cf] = (g < GG) ? Bias[n * GG + g] : 0.0f;
    }
    short8 areg[2][4];
    conv_x(raw, areg);

    __syncthreads();

    f32x4 acc[2][7];
    #pragma unroll
    for (int rf = 0; rf < 2; ++rf)
        #pragma unroll
        for (int cf = 0; cf < 7; ++cf)
            acc[rf][cf] = (f32x4){0.f, 0.f, 0.f, 0.f};

    #pragma unroll
    for (int cf = 0; cf < 7; ++cf) {
        const int g    = cf * 16 + l15;
        const int rowb = g * ROWB;
        const int swz  = (g & 7) << 4;
        #pragma unroll
        for (int ks = 0; ks < 4; ++ks) {
            const int off = rowb + (((lhi * 16) + ks * 64) ^ swz);
            const i32x4 braw = *reinterpret_cast<const i32x4*>(smem + off);
            const short8 bfrag = __builtin_bit_cast(short8, braw);
            acc[0][cf] = __builtin_amdgcn_mfma_f32_16x16x32_bf16(areg[0][ks], bfrag, acc[0][cf], 0, 0, 0);
            acc[1][cf] = __builtin_amdgcn_mfma_f32_16x16x32_bf16(areg[1][ks], bfrag, acc[1][cf], 0, 0, 0);
        }
    }

    __syncthreads();

    float* lds_f = reinterpret_cast<float*>(smem + wid * 6400);
    #pragma unroll
    for (int rf = 0; rf < 2; ++rf) {
        #pragma unroll
        for (int cf = 0; cf < 7; ++cf) {
            const int g = cf * 16 + l15;
            if (g < GG) {
                #pragma unroll
                for (int j = 0; j < 4; ++j)
                    lds_f[(lhi * 4 + j) * GG + g] = acc[rf][cf][j] + bias[cf];
            }
        }
        WAIT_LGKM0();
        const char* rgn = smem + wid * 6400;
        char* dst = (char*)(Out + ((size_t)n * BSZ + rowbase + rf * 16) * GG);
        #pragma unroll
        for (int it = 0; it < 7; ++it) {
            const int c = it * 64 + lane;
            if (c < 400) {
                const i32x4 v = *reinterpret_cast<const i32x4*>(rgn + c * 16);
                *reinterpret_cast<i32x4*>(dst + c * 16) = v;
            }
        }
        WAIT_LGKM0();
    }
}

extern "C" void kernel_launch(void* const* d_in, const int* in_sizes, int n_in,
                              void* d_out, int out_size, void* d_ws, size_t ws_size,
                              hipStream_t stream) {
    (void)in_sizes; (void)n_in; (void)out_size;
    const float* X    = (const float*)d_in[0];
    const float* W    = (const float*)d_in[1];
    const float* Bias = (const float*)d_in[2];
    float* Out        = (float*)d_out;
    const size_t wsneed = (size_t)NB * WIMG;   // 5,734,400 B
    if (ws_size >= wsneed) {
        wconv_kernel<<<(NB * WROWS * 16 + 255) / 256, 256, 0, stream>>>(W, (unsigned char*)d_ws);
        mtl_heads_pipe<<<dim3(NBLK), 256, 0, stream>>>(X, Bias, (const unsigned char*)d_ws, Out);
    } else {
        mtl_heads_fallback<<<dim3(16, NB), 256, 0, stream>>>(X, W, Bias, Out);
    }
}

// Round 15
// 73.339 us; speedup vs baseline: 3.1900x; 1.4696x over previous
//
#include <hip/hip_runtime.h>
#include <hip/hip_bf16.h>

// Problem constants (reference: B=2048, N_BINS=200, D=128, G=100)
#define NB    200
#define BSZ   2048
#define DD    128
#define GG    100
#define WROWS 112                 // gene rows padded to 7 frags of 16
#define ROWB  256                 // bytes per LDS W row (128 bf16)
#define WIMG  (WROWS * ROWB)      // 28672 B per-bin W image
#define NTILE (NB * 16)           // 3200 (mtile fastest: tile = n*16 + mtile)
#define NBLK  512                 // grid size == tile stride (2 blocks/CU)

typedef __attribute__((ext_vector_type(8))) short  short8;  // 8 bf16 (MFMA A/B frag)
typedef __attribute__((ext_vector_type(4))) float  f32x4;   // MFMA C/D frag
typedef __attribute__((ext_vector_type(4))) int    i32x4;   // 16B chunk

// round-to-nearest-even f32 -> bf16, two at a time packed into a dword
__device__ __forceinline__ unsigned f2bf_pack(float lo, float hi) {
    unsigned ulo = __builtin_bit_cast(unsigned, lo);
    ulo += 0x7FFFu + ((ulo >> 16) & 1u);
    unsigned uhi = __builtin_bit_cast(unsigned, hi);
    uhi += 0x7FFFu + ((uhi >> 16) & 1u);
    return (ulo >> 16) | (uhi & 0xFFFF0000u);
}

__device__ __forceinline__ void gload_lds16(const void* g, void* l) {
    __builtin_amdgcn_global_load_lds(
        (const __attribute__((address_space(1))) unsigned int*)g,
        (__attribute__((address_space(3))) unsigned int*)l, 16, 0, 0);
}

// Wave-level LDS drain (scratch is wave-private): lgkmcnt(0) only.
#define WAIT_LGKM0() do { asm volatile("" ::: "memory");     \
                          __builtin_amdgcn_s_waitcnt(0xC07F);\
                          __builtin_amdgcn_sched_barrier(0); \
                          __builtin_amdgcn_wave_barrier();   \
                          asm volatile("" ::: "memory"); } while (0)

// Cross-wave barrier WITHOUT vmcnt drain: prefetch loads stay in flight.
#define BARRIER_LGKM() do { asm volatile("" ::: "memory");      \
                            __builtin_amdgcn_s_waitcnt(0xC07F); \
                            __builtin_amdgcn_s_barrier();       \
                            __builtin_amdgcn_sched_barrier(0);  \
                            asm volatile("" ::: "memory"); } while (0)

// Iteration-end barrier, COUNTED: per wave the 14 newest VMEM ops are this
// tile's NT stores (issue order: 7 staging + 16 X + 7 bias + 14 stores;
// vmcnt retires in order). vmcnt(14) => staging/X/bias retired, store-acks
// stay in flight. Store data is already in VGPRs (lgkmcnt(0) drained the
// LDS reads), so next-tile staging may overwrite scratch safely.
// r11/r13 CONFOUND NOTE: the earlier "vmcnt(14) regression" was actually
// __launch_bounds__(256,3) forcing VGPR 84 + scratch spills. This is the
// first clean test on the r12 base.
#define BARRIER_VM14() do { asm volatile("s_waitcnt vmcnt(14)" ::: "memory"); \
                            __builtin_amdgcn_s_barrier();        \
                            __builtin_amdgcn_sched_barrier(0);   \
                            asm volatile("" ::: "memory"); } while (0)

// Prologue barrier: full drain.
#define BARRIER_VM0() do { asm volatile("s_waitcnt vmcnt(0) lgkmcnt(0)" ::: "memory"); \
                           __builtin_amdgcn_s_barrier();        \
                           __builtin_amdgcn_sched_barrier(0);   \
                           asm volatile("" ::: "memory"); } while (0)

// NOTE (r11/r13/r14 lessons): keep __launch_bounds__(256,2) — (256,3) makes
// the register allocator spill the X prefetch (VGPR 84, +250 MB traffic).
// Keep grid 512 + 64-tile XCD chunks — grid 768 / 96-tile chunks overflow
// the 4 MB per-XCD L2 (FETCH +20 MB) and regress.

// ---------------------------------------------------------------------------
// Pre-pass: W f32 [NB][GG][DD] -> bf16 swizzled per-bin images in d_ws.
// byte off = row*256 + ((granule*16) ^ ((row&7)<<4)), rows >= GG zeroed.
// ---------------------------------------------------------------------------
__global__ __launch_bounds__(256) void wconv_kernel(
    const float* __restrict__ W, unsigned char* __restrict__ ws)
{
    const int gidx = blockIdx.x * 256 + threadIdx.x;
    if (gidx >= NB * WROWS * 16) return;
    const int gr  = gidx & 15;
    const int row = (gidx >> 4) % WROWS;
    const int n   = gidx / (WROWS * 16);
    i32x4 pack = (i32x4){0, 0, 0, 0};
    if (row < GG) {
        const float* src = W + ((size_t)n * GG + row) * DD + gr * 8;
        const f32x4 a = *reinterpret_cast<const f32x4*>(src);
        const f32x4 b = *reinterpret_cast<const f32x4*>(src + 4);
        pack.x = (int)f2bf_pack(a[0], a[1]);
        pack.y = (int)f2bf_pack(a[2], a[3]);
        pack.z = (int)f2bf_pack(b[0], b[1]);
        pack.w = (int)f2bf_pack(b[2], b[3]);
    }
    const int off = row * ROWB + ((gr * 16) ^ ((row & 7) << 4));
    *reinterpret_cast<i32x4*>(ws + (size_t)n * WIMG + off) = pack;
}

// ---------------------------------------------------------------------------
// Pipelined main kernel helpers (r12 proven structure)
// ---------------------------------------------------------------------------
__device__ __forceinline__ void stage_tile(char* buf, const unsigned char* WS,
                                           int n, int lane, int wid) {
    const unsigned char* src = WS + (size_t)n * WIMG;
    #pragma unroll
    for (int i = 0; i < 7; ++i) {
        const int c = i * 4 + wid;                    // wave-chunk 0..27 (7/wave uniform)
        gload_lds16(src + c * 1024 + lane * 16, buf + c * 1024);
    }
}

__device__ __forceinline__ void load_x(f32x4 (&raw)[2][4][2], const float* X,
                                       int tile, int wid, int l15, int lhi) {
    const int n = tile >> 4;
    const int rowbase = (tile & 15) * 128 + wid * 32;
    #pragma unroll
    for (int rf = 0; rf < 2; ++rf) {
        const float* xrow = X + ((size_t)(rowbase + rf * 16 + l15) * NB + n) * DD + lhi * 8;
        #pragma unroll
        for (int ks = 0; ks < 4; ++ks) {
            raw[rf][ks][0] = *reinterpret_cast<const f32x4*>(xrow + ks * 32);
            raw[rf][ks][1] = *reinterpret_cast<const f32x4*>(xrow + ks * 32 + 4);
        }
    }
}

__device__ __forceinline__ void conv_x(const f32x4 (&raw)[2][4][2],
                                       short8 (&areg)[2][4]) {
    #pragma unroll
    for (int rf = 0; rf < 2; ++rf)
        #pragma unroll
        for (int ks = 0; ks < 4; ++ks) {
            const f32x4 a = raw[rf][ks][0];
            const f32x4 b = raw[rf][ks][1];
            i32x4 pk;
            pk.x = (int)f2bf_pack(a[0], a[1]);
            pk.y = (int)f2bf_pack(a[2], a[3]);
            pk.z = (int)f2bf_pack(b[0], b[1]);
            pk.w = (int)f2bf_pack(b[2], b[3]);
            areg[rf][ks] = __builtin_bit_cast(short8, pk);
        }
}

// One tile: prefetch next (W->bufN async, X->raw), MFMA current from bufC,
// epilogue through bufC scratch, convert raw->aregN, counted end barrier.
__device__ __forceinline__ bool tile_body(int tile,
    const float* __restrict__ X, const float* __restrict__ Bias,
    float* __restrict__ Out, const unsigned char* __restrict__ WS,
    char* bufC, char* bufN,
    short8 (&aregC)[2][4], short8 (&aregN)[2][4], f32x4 (&raw)[2][4][2],
    int lane, int wid, int l15, int lhi)
{
    const int n       = tile >> 4;
    const int rowbase = (tile & 15) * 128 + wid * 32;
    const int tn      = tile + NBLK;
    const bool hasnext = (tn < NTILE);

    // 1. issue next-tile prefetch FIRST (hides HBM latency under this tile)
    if (hasnext) {
        stage_tile(bufN, WS, tn >> 4, lane, wid);
        load_x(raw, X, tn, wid, l15, lhi);
    }
    float bias[7];
    #pragma unroll
    for (int cf = 0; cf < 7; ++cf) {
        const int g = cf * 16 + l15;
        bias[cf] = (g < GG) ? Bias[n * GG + g] : 0.0f;
    }

    // 2. MFMA: 2 row-frags x 7 col-frags x 4 k-steps from bufC
    f32x4 acc[2][7];
    #pragma unroll
    for (int rf = 0; rf < 2; ++rf)
        #pragma unroll
        for (int cf = 0; cf < 7; ++cf)
            acc[rf][cf] = (f32x4){0.f, 0.f, 0.f, 0.f};

    #pragma unroll
    for (int cf = 0; cf < 7; ++cf) {
        const int g    = cf * 16 + l15;          // B-frag: gene row of W
        const int rowb = g * ROWB;
        const int swz  = (g & 7) << 4;
        #pragma unroll
        for (int ks = 0; ks < 4; ++ks) {
            const int off = rowb + (((lhi * 16) + ks * 64) ^ swz);
            const i32x4 braw = *reinterpret_cast<const i32x4*>(bufC + off);  // ds_read_b128
            const short8 bfrag = __builtin_bit_cast(short8, braw);
            acc[0][cf] = __builtin_amdgcn_mfma_f32_16x16x32_bf16(aregC[0][ks], bfrag, acc[0][cf], 0, 0, 0);
            acc[1][cf] = __builtin_amdgcn_mfma_f32_16x16x32_bf16(aregC[1][ks], bfrag, acc[1][cf], 0, 0, 0);
        }
    }

    // 3. all waves done reading bufC (raw barrier: prefetch stays in flight)
    BARRIER_LGKM();

    // 4. epilogue: wave-private transpose in bufC scratch -> contiguous NT stores
    float* lds_f = reinterpret_cast<float*>(bufC + wid * 6400);
    #pragma unroll
    for (int rf = 0; rf < 2; ++rf) {
        #pragma unroll
        for (int cf = 0; cf < 7; ++cf) {
            const int g = cf * 16 + l15;
            if (g < GG) {
                #pragma unroll
                for (int j = 0; j < 4; ++j)
                    lds_f[(lhi * 4 + j) * GG + g] = acc[rf][cf][j] + bias[cf];
            }
        }
        WAIT_LGKM0();
        const char* rgn = bufC + wid * 6400;
        char* dst = (char*)(Out + ((size_t)n * BSZ + rowbase + rf * 16) * GG);
        #pragma unroll
        for (int it = 0; it < 7; ++it) {
            const int c = it * 64 + lane;         // 16B-chunk index, 400 total
            if (c < 400) {
                const i32x4 v = *reinterpret_cast<const i32x4*>(rgn + c * 16);
                __builtin_nontemporal_store(v, reinterpret_cast<i32x4*>(dst + c * 16));
            }
        }
        WAIT_LGKM0();   // scratch reads done before rf=1 overwrites
    }

    // 5. convert next tile's X (compiler inserts the counted vmcnt for raw)
    if (hasnext) conv_x(raw, aregN);

    // 6. iteration end: staging + X + bias retired for all waves; the 14 NT
    //    store-acks stay in flight (the r12 BARRIER_VM0 waited them — ~600-900
    //    cycles of pure store-ack latency per tile removed).
    BARRIER_VM14();
    return hasnext;
}

__global__ __launch_bounds__(256, 2) void mtl_heads_pipe(
    const float* __restrict__ X, const float* __restrict__ Bias,
    const unsigned char* __restrict__ WS, float* __restrict__ Out)
{
    const int tid  = threadIdx.x;
    const int lane = tid & 63;
    const int wid  = tid >> 6;
    const int l15  = lane & 15;
    const int lhi  = lane >> 4;

    __shared__ __align__(16) char smem[2 * WIMG];   // 57344 B: double-buffered W
    char* bufA = smem;
    char* bufB = smem + WIMG;

    short8 aregA[2][4], aregB[2][4];
    f32x4  raw[2][4][2];

    // XCD-aware swizzle (T1, r12-proven): XCD k's 64 blocks cover 64
    // CONSECUTIVE tiles (= 4 bins) per pipeline step -> X-slab + W images
    // fit its private 4 MB L2. Bijective on [0,512).
    int t = ((blockIdx.x & 7) << 6) + (blockIdx.x >> 3);

    // prologue: stage tile t0 into bufA, load its X, full drain, convert
    stage_tile(bufA, WS, t >> 4, lane, wid);
    load_x(raw, X, t, wid, l15, lhi);
    BARRIER_VM0();
    conv_x(raw, aregA);

    // ping-pong main loop (tile count uniform across waves -> barriers lockstep)
    for (;;) {
        if (!tile_body(t, X, Bias, Out, WS, bufA, bufB, aregA, aregB, raw,
                       lane, wid, l15, lhi)) break;
        t += NBLK;
        if (!tile_body(t, X, Bias, Out, WS, bufB, bufA, aregB, aregA, raw,
                       lane, wid, l15, lhi)) break;
        t += NBLK;
    }
}

// ---------------------------------------------------------------------------
// Fallback (no workspace): single-tile kernel, in-kernel W convert.
// ---------------------------------------------------------------------------
__global__ __launch_bounds__(256, 4) void mtl_heads_fallback(
    const float* __restrict__ X, const float* __restrict__ W,
    const float* __restrict__ Bias, float* __restrict__ Out)
{
    const int n     = blockIdx.y;
    const int mtile = blockIdx.x;
    const int tid   = threadIdx.x;
    const int lane  = tid & 63;
    const int wid   = tid >> 6;
    const int l15   = lane & 15;
    const int lhi   = lane >> 4;

    __shared__ __align__(16) char smem[WIMG];

    {
        const int rsub = tid >> 4;
        const int k0   = (tid & 15) * 8;
        #pragma unroll
        for (int it = 0; it < 7; ++it) {
            const int row = it * 16 + rsub;
            i32x4 pack = (i32x4){0, 0, 0, 0};
            if (row < GG) {
                const float* s = W + ((size_t)n * GG + row) * DD + k0;
                const f32x4 a = *reinterpret_cast<const f32x4*>(s);
                const f32x4 b = *reinterpret_cast<const f32x4*>(s + 4);
                pack.x = (int)f2bf_pack(a[0], a[1]);
                pack.y = (int)f2bf_pack(a[2], a[3]);
                pack.z = (int)f2bf_pack(b[0], b[1]);
                pack.w = (int)f2bf_pack(b[2], b[3]);
            }
            const int off = row * ROWB + ((k0 * 2) ^ ((row & 7) << 4));
            *reinterpret_cast<i32x4*>(smem + off) = pack;
        }
    }

    const int rowbase = mtile * 128 + wid * 32;
    f32x4 raw[2][4][2];
    load_x(raw, X, n * 16 + mtile, wid, l15, lhi);
    float bias[7];
    #pragma unroll
    for (int cf = 0; cf < 7; ++cf) {
        const int g = cf * 16 + l15;
        bias[cf] = (g < GG) ? Bias[n * GG + g] : 0.0f;
    }
    short8 areg[2][4];
    conv_x(raw, areg);

    __syncthreads();

    f32x4 acc[2][7];
    #pragma unroll
    for (int rf = 0; rf < 2; ++rf)
        #pragma unroll
        for (int cf = 0; cf < 7; ++cf)
            acc[rf][cf] = (f32x4){0.f, 0.f, 0.f, 0.f};

    #pragma unroll
    for (int cf = 0; cf < 7; ++cf) {
        const int g    = cf * 16 + l15;
        const int rowb = g * ROWB;
        const int swz  = (g & 7) << 4;
        #pragma unroll
        for (int ks = 0; ks < 4; ++ks) {
            const int off = rowb + (((lhi * 16) + ks * 64) ^ swz);
            const i32x4 braw = *reinterpret_cast<const i32x4*>(smem + off);
            const short8 bfrag = __builtin_bit_cast(short8, braw);
            acc[0][cf] = __builtin_amdgcn_mfma_f32_16x16x32_bf16(areg[0][ks], bfrag, acc[0][cf], 0, 0, 0);
            acc[1][cf] = __builtin_amdgcn_mfma_f32_16x16x32_bf16(areg[1][ks], bfrag, acc[1][cf], 0, 0, 0);
        }
    }

    __syncthreads();

    float* lds_f = reinterpret_cast<float*>(smem + wid * 6400);
    #pragma unroll
    for (int rf = 0; rf < 2; ++rf) {
        #pragma unroll
        for (int cf = 0; cf < 7; ++cf) {
            const int g = cf * 16 + l15;
            if (g < GG) {
                #pragma unroll
                for (int j = 0; j < 4; ++j)
                    lds_f[(lhi * 4 + j) * GG + g] = acc[rf][cf][j] + bias[cf];
            }
        }
        WAIT_LGKM0();
        const char* rgn = smem + wid * 6400;
        char* dst = (char*)(Out + ((size_t)n * BSZ + rowbase + rf * 16) * GG);
        #pragma unroll
        for (int it = 0; it < 7; ++it) {
            const int c = it * 64 + lane;
            if (c < 400) {
                const i32x4 v = *reinterpret_cast<const i32x4*>(rgn + c * 16);
                *reinterpret_cast<i32x4*>(dst + c * 16) = v;
            }
        }
        WAIT_LGKM0();
    }
}

extern "C" void kernel_launch(void* const* d_in, const int* in_sizes, int n_in,
                              void* d_out, int out_size, void* d_ws, size_t ws_size,
                              hipStream_t stream) {
    (void)in_sizes; (void)n_in; (void)out_size;
    const float* X    = (const float*)d_in[0];
    const float* W    = (const float*)d_in[1];
    const float* Bias = (const float*)d_in[2];
    float* Out        = (float*)d_out;
    const size_t wsneed = (size_t)NB * WIMG;   // 5,734,400 B
    if (ws_size >= wsneed) {
        wconv_kernel<<<(NB * WROWS * 16 + 255) / 256, 256, 0, stream>>>(W, (unsigned char*)d_ws);
        mtl_heads_pipe<<<dim3(NBLK), 256, 0, stream>>>(X, Bias, (const unsigned char*)d_ws, Out);
    } else {
        mtl_heads_fallback<<<dim3(16, NB), 256, 0, stream>>>(X, W, Bias, Out);
    }
}

// Round 16
// 72.463 us; speedup vs baseline: 3.2285x; 1.0121x over previous
//
#include <hip/hip_runtime.h>
#include <hip/hip_bf16.h>

// Problem constants (reference: B=2048, N_BINS=200, D=128, G=100)
#define NB    200
#define BSZ   2048
#define DD    128
#define GG    100
#define WROWS 112                 // gene rows padded to 7 frags of 16
#define ROWB  256                 // bytes per LDS W row (128 bf16)
#define WIMG  (WROWS * ROWB)      // 28672 B per-bin W image
#define NTILE (NB * 16)           // 3200 (tile = n*16 + mtile)
#define NBLK  512                 // grid size (2 blocks/CU)

typedef __attribute__((ext_vector_type(8))) short  short8;  // 8 bf16 (MFMA A/B frag)
typedef __attribute__((ext_vector_type(4))) float  f32x4;   // MFMA C/D frag
typedef __attribute__((ext_vector_type(4))) int    i32x4;   // 16B chunk

// round-to-nearest-even f32 -> bf16, two at a time packed into a dword
__device__ __forceinline__ unsigned f2bf_pack(float lo, float hi) {
    unsigned ulo = __builtin_bit_cast(unsigned, lo);
    ulo += 0x7FFFu + ((ulo >> 16) & 1u);
    unsigned uhi = __builtin_bit_cast(unsigned, hi);
    uhi += 0x7FFFu + ((uhi >> 16) & 1u);
    return (ulo >> 16) | (uhi & 0xFFFF0000u);
}

__device__ __forceinline__ void gload_lds16(const void* g, void* l) {
    __builtin_amdgcn_global_load_lds(
        (const __attribute__((address_space(1))) unsigned int*)g,
        (__attribute__((address_space(3))) unsigned int*)l, 16, 0, 0);
}

// Wave-level LDS drain (scratch is wave-private): lgkmcnt(0) only.
#define WAIT_LGKM0() do { asm volatile("" ::: "memory");     \
                          __builtin_amdgcn_s_waitcnt(0xC07F);\
                          __builtin_amdgcn_sched_barrier(0); \
                          __builtin_amdgcn_wave_barrier();   \
                          asm volatile("" ::: "memory"); } while (0)

// Cross-wave barrier WITHOUT vmcnt drain: prefetch loads stay in flight.
#define BARRIER_LGKM() do { asm volatile("" ::: "memory");      \
                            __builtin_amdgcn_s_waitcnt(0xC07F); \
                            __builtin_amdgcn_s_barrier();       \
                            __builtin_amdgcn_sched_barrier(0);  \
                            asm volatile("" ::: "memory"); } while (0)

// Iteration-end barrier, COUNTED (r15-proven): per wave the 14 newest VMEM
// ops are this tile's NT stores (issue order: [7 staging if bin-change] +
// 16 X + 7 bias + 14 stores; vmcnt retires in order). vmcnt(14) => staging/
// X/bias retired, store-acks stay in flight.
#define BARRIER_VM14() do { asm volatile("s_waitcnt vmcnt(14)" ::: "memory"); \
                            __builtin_amdgcn_s_barrier();        \
                            __builtin_amdgcn_sched_barrier(0);   \
                            asm volatile("" ::: "memory"); } while (0)

// Prologue barrier: full drain.
#define BARRIER_VM0() do { asm volatile("s_waitcnt vmcnt(0) lgkmcnt(0)" ::: "memory"); \
                           __builtin_amdgcn_s_barrier();        \
                           __builtin_amdgcn_sched_barrier(0);   \
                           asm volatile("" ::: "memory"); } while (0)

// NOTE (r11/r13/r14 lessons): keep __launch_bounds__(256,2) — (256,3) makes
// the register allocator spill the X prefetch (VGPR 84, +250 MB traffic).
// Grid 512 + XCD-contiguous tile ranges; runs give W reuse IN LDS.

// ---------------------------------------------------------------------------
// Pre-pass: W f32 [NB][GG][DD] -> bf16 swizzled per-bin images in d_ws.
// byte off = row*256 + ((granule*16) ^ ((row&7)<<4)), rows >= GG zeroed.
// ---------------------------------------------------------------------------
__global__ __launch_bounds__(256) void wconv_kernel(
    const float* __restrict__ W, unsigned char* __restrict__ ws)
{
    const int gidx = blockIdx.x * 256 + threadIdx.x;
    if (gidx >= NB * WROWS * 16) return;
    const int gr  = gidx & 15;
    const int row = (gidx >> 4) % WROWS;
    const int n   = gidx / (WROWS * 16);
    i32x4 pack = (i32x4){0, 0, 0, 0};
    if (row < GG) {
        const float* src = W + ((size_t)n * GG + row) * DD + gr * 8;
        const f32x4 a = *reinterpret_cast<const f32x4*>(src);
        const f32x4 b = *reinterpret_cast<const f32x4*>(src + 4);
        pack.x = (int)f2bf_pack(a[0], a[1]);
        pack.y = (int)f2bf_pack(a[2], a[3]);
        pack.z = (int)f2bf_pack(b[0], b[1]);
        pack.w = (int)f2bf_pack(b[2], b[3]);
    }
    const int off = row * ROWB + ((gr * 16) ^ ((row & 7) << 4));
    *reinterpret_cast<i32x4*>(ws + (size_t)n * WIMG + off) = pack;
}

// ---------------------------------------------------------------------------
// Main kernel helpers (r15 structure)
// ---------------------------------------------------------------------------
__device__ __forceinline__ void stage_tile(char* buf, const unsigned char* WS,
                                           int n, int lane, int wid) {
    const unsigned char* src = WS + (size_t)n * WIMG;
    #pragma unroll
    for (int i = 0; i < 7; ++i) {
        const int c = i * 4 + wid;                    // wave-chunk 0..27 (7/wave uniform)
        gload_lds16(src + c * 1024 + lane * 16, buf + c * 1024);
    }
}

__device__ __forceinline__ void load_x(f32x4 (&raw)[2][4][2], const float* X,
                                       int tile, int wid, int l15, int lhi) {
    const int n = tile >> 4;
    const int rowbase = (tile & 15) * 128 + wid * 32;
    #pragma unroll
    for (int rf = 0; rf < 2; ++rf) {
        const float* xrow = X + ((size_t)(rowbase + rf * 16 + l15) * NB + n) * DD + lhi * 8;
        #pragma unroll
        for (int ks = 0; ks < 4; ++ks) {
            raw[rf][ks][0] = *reinterpret_cast<const f32x4*>(xrow + ks * 32);
            raw[rf][ks][1] = *reinterpret_cast<const f32x4*>(xrow + ks * 32 + 4);
        }
    }
}

__device__ __forceinline__ void conv_x(const f32x4 (&raw)[2][4][2],
                                       short8 (&areg)[2][4]) {
    #pragma unroll
    for (int rf = 0; rf < 2; ++rf)
        #pragma unroll
        for (int ks = 0; ks < 4; ++ks) {
            const f32x4 a = raw[rf][ks][0];
            const f32x4 b = raw[rf][ks][1];
            i32x4 pk;
            pk.x = (int)f2bf_pack(a[0], a[1]);
            pk.y = (int)f2bf_pack(a[2], a[3]);
            pk.z = (int)f2bf_pack(b[0], b[1]);
            pk.w = (int)f2bf_pack(b[2], b[3]);
            areg[rf][ks] = __builtin_bit_cast(short8, pk);
        }
}

// ---------------------------------------------------------------------------
// Consecutive-run main kernel: each block owns 6-7 CONSECUTIVE tiles; W is
// staged only when the bin changes within the run (~740 stagings total vs
// 3200 in r15 -> -70 MB VMEM-path traffic). Buffer roles: wbuf = current W
// (persists across same-bin tiles); epilogue scratch = the buffer being
// retired (wbuf on bin-change, post-BARRIER_LGKM) or the free obuf.
// ---------------------------------------------------------------------------
__global__ __launch_bounds__(256, 2) void mtl_heads_runs(
    const float* __restrict__ X, const float* __restrict__ Bias,
    const unsigned char* __restrict__ WS, float* __restrict__ Out)
{
    const int tid  = threadIdx.x;
    const int lane = tid & 63;
    const int wid  = tid >> 6;
    const int l15  = lane & 15;
    const int lhi  = lane >> 4;

    __shared__ __align__(16) char smem[2 * WIMG];   // 57344 B
    char* wbuf = smem;          // current bin's W
    char* obuf = smem + WIMG;   // free / next-W buffer

    // XCD swizzle: s consecutive within an XCD -> each XCD owns a contiguous
    // tile range. Heavy (7-tile) blocks every 4th s (no per-XCD tail skew):
    // start(s) = 6*s + ceil(s/4), cnt = (s%4==0) ? 7 : 6; total = 3200.
    const int s   = ((blockIdx.x & 7) << 6) + (blockIdx.x >> 3);
    const int cnt = ((s & 3) == 0) ? 7 : 6;
    int t = 6 * s + ((s + 3) >> 2);

    // prologue: stage W(bin(t)) + first X tile, full drain, convert
    stage_tile(wbuf, WS, t >> 4, lane, wid);
    f32x4 raw[2][4][2];
    load_x(raw, X, t, wid, l15, lhi);
    BARRIER_VM0();
    short8 areg[2][4];
    conv_x(raw, areg);

    for (int i = 0; i < cnt; ++i, ++t) {
        const int  n       = t >> 4;
        const int  rowbase = (t & 15) * 128 + wid * 32;
        const bool hasnext = (i + 1 < cnt);
        const bool binchg  = hasnext && (((t + 1) & 15) == 0);

        // 1. prefetch: W only on bin change; X always (hides HBM latency)
        if (binchg)  stage_tile(obuf, WS, (t + 1) >> 4, lane, wid);
        if (hasnext) load_x(raw, X, t + 1, wid, l15, lhi);
        float bias[7];
        #pragma unroll
        for (int cf = 0; cf < 7; ++cf) {
            const int g = cf * 16 + l15;
            bias[cf] = (g < GG) ? Bias[n * GG + g] : 0.0f;
        }

        // 2. MFMA: 2 row-frags x 7 col-frags x 4 k-steps from wbuf
        f32x4 acc[2][7];
        #pragma unroll
        for (int rf = 0; rf < 2; ++rf)
            #pragma unroll
            for (int cf = 0; cf < 7; ++cf)
                acc[rf][cf] = (f32x4){0.f, 0.f, 0.f, 0.f};

        #pragma unroll
        for (int cf = 0; cf < 7; ++cf) {
            const int g    = cf * 16 + l15;          // B-frag: gene row of W
            const int rowb = g * ROWB;
            const int swz  = (g & 7) << 4;
            #pragma unroll
            for (int ks = 0; ks < 4; ++ks) {
                const int off = rowb + (((lhi * 16) + ks * 64) ^ swz);
                const i32x4 braw = *reinterpret_cast<const i32x4*>(wbuf + off);  // ds_read_b128
                const short8 bfrag = __builtin_bit_cast(short8, braw);
                acc[0][cf] = __builtin_amdgcn_mfma_f32_16x16x32_bf16(areg[0][ks], bfrag, acc[0][cf], 0, 0, 0);
                acc[1][cf] = __builtin_amdgcn_mfma_f32_16x16x32_bf16(areg[1][ks], bfrag, acc[1][cf], 0, 0, 0);
            }
        }

        // 3. all waves done reading wbuf (prefetch stays in flight)
        BARRIER_LGKM();

        // 4. epilogue: scratch = retiring wbuf (bin change) or free obuf;
        //    never the staging destination.
        char* scratch = (binchg ? wbuf : obuf) + wid * 6400;
        float* lds_f = reinterpret_cast<float*>(scratch);
        #pragma unroll
        for (int rf = 0; rf < 2; ++rf) {
            #pragma unroll
            for (int cf = 0; cf < 7; ++cf) {
                const int g = cf * 16 + l15;
                if (g < GG) {
                    #pragma unroll
                    for (int j = 0; j < 4; ++j)
                        lds_f[(lhi * 4 + j) * GG + g] = acc[rf][cf][j] + bias[cf];
                }
            }
            WAIT_LGKM0();
            char* dst = (char*)(Out + ((size_t)n * BSZ + rowbase + rf * 16) * GG);
            #pragma unroll
            for (int it = 0; it < 7; ++it) {
                const int c = it * 64 + lane;         // 16B-chunk index, 400 total
                if (c < 400) {
                    const i32x4 v = *reinterpret_cast<const i32x4*>(scratch + c * 16);
                    __builtin_nontemporal_store(v, reinterpret_cast<i32x4*>(dst + c * 16));
                }
            }
            WAIT_LGKM0();   // scratch reads done before rf=1 overwrites
        }

        // 5. convert next tile's X (compiler inserts counted vmcnt for raw)
        if (hasnext) conv_x(raw, areg);

        // 6. iteration end: staging + X + bias retired for all waves; the 14
        //    NT store-acks stay in flight.
        BARRIER_VM14();

        // 7. swap buffer roles on bin change (obuf now holds the new W)
        if (binchg) { char* tmp = wbuf; wbuf = obuf; obuf = tmp; }
    }
}

// ---------------------------------------------------------------------------
// Fallback (no workspace): single-tile kernel, in-kernel W convert.
// ---------------------------------------------------------------------------
__global__ __launch_bounds__(256, 4) void mtl_heads_fallback(
    const float* __restrict__ X, const float* __restrict__ W,
    const float* __restrict__ Bias, float* __restrict__ Out)
{
    const int n     = blockIdx.y;
    const int mtile = blockIdx.x;
    const int tid   = threadIdx.x;
    const int lane  = tid & 63;
    const int wid   = tid >> 6;
    const int l15   = lane & 15;
    const int lhi   = lane >> 4;

    __shared__ __align__(16) char smem[WIMG];

    {
        const int rsub = tid >> 4;
        const int k0   = (tid & 15) * 8;
        #pragma unroll
        for (int it = 0; it < 7; ++it) {
            const int row = it * 16 + rsub;
            i32x4 pack = (i32x4){0, 0, 0, 0};
            if (row < GG) {
                const float* s = W + ((size_t)n * GG + row) * DD + k0;
                const f32x4 a = *reinterpret_cast<const f32x4*>(s);
                const f32x4 b = *reinterpret_cast<const f32x4*>(s + 4);
                pack.x = (int)f2bf_pack(a[0], a[1]);
                pack.y = (int)f2bf_pack(a[2], a[3]);
                pack.z = (int)f2bf_pack(b[0], b[1]);
                pack.w = (int)f2bf_pack(b[2], b[3]);
            }
            const int off = row * ROWB + ((k0 * 2) ^ ((row & 7) << 4));
            *reinterpret_cast<i32x4*>(smem + off) = pack;
        }
    }

    const int rowbase = mtile * 128 + wid * 32;
    f32x4 raw[2][4][2];
    load_x(raw, X, n * 16 + mtile, wid, l15, lhi);
    float bias[7];
    #pragma unroll
    for (int cf = 0; cf < 7; ++cf) {
        const int g = cf * 16 + l15;
        bias[cf] = (g < GG) ? Bias[n * GG + g] : 0.0f;
    }
    short8 areg[2][4];
    conv_x(raw, areg);

    __syncthreads();

    f32x4 acc[2][7];
    #pragma unroll
    for (int rf = 0; rf < 2; ++rf)
        #pragma unroll
        for (int cf = 0; cf < 7; ++cf)
            acc[rf][cf] = (f32x4){0.f, 0.f, 0.f, 0.f};

    #pragma unroll
    for (int cf = 0; cf < 7; ++cf) {
        const int g    = cf * 16 + l15;
        const int rowb = g * ROWB;
        const int swz  = (g & 7) << 4;
        #pragma unroll
        for (int ks = 0; ks < 4; ++ks) {
            const int off = rowb + (((lhi * 16) + ks * 64) ^ swz);
            const i32x4 braw = *reinterpret_cast<const i32x4*>(smem + off);
            const short8 bfrag = __builtin_bit_cast(short8, braw);
            acc[0][cf] = __builtin_amdgcn_mfma_f32_16x16x32_bf16(areg[0][ks], bfrag, acc[0][cf], 0, 0, 0);
            acc[1][cf] = __builtin_amdgcn_mfma_f32_16x16x32_bf16(areg[1][ks], bfrag, acc[1][cf], 0, 0, 0);
        }
    }

    __syncthreads();

    float* lds_f = reinterpret_cast<float*>(smem + wid * 6400);
    #pragma unroll
    for (int rf = 0; rf < 2; ++rf) {
        #pragma unroll
        for (int cf = 0; cf < 7; ++cf) {
            const int g = cf * 16 + l15;
            if (g < GG) {
                #pragma unroll
                for (int j = 0; j < 4; ++j)
                    lds_f[(lhi * 4 + j) * GG + g] = acc[rf][cf][j] + bias[cf];
            }
        }
        WAIT_LGKM0();
        const char* rgn = smem + wid * 6400;
        char* dst = (char*)(Out + ((size_t)n * BSZ + rowbase + rf * 16) * GG);
        #pragma unroll
        for (int it = 0; it < 7; ++it) {
            const int c = it * 64 + lane;
            if (c < 400) {
                const i32x4 v = *reinterpret_cast<const i32x4*>(rgn + c * 16);
                *reinterpret_cast<i32x4*>(dst + c * 16) = v;
            }
        }
        WAIT_LGKM0();
    }
}

extern "C" void kernel_launch(void* const* d_in, const int* in_sizes, int n_in,
                              void* d_out, int out_size, void* d_ws, size_t ws_size,
                              hipStream_t stream) {
    (void)in_sizes; (void)n_in; (void)out_size;
    const float* X    = (const float*)d_in[0];
    const float* W    = (const float*)d_in[1];
    const float* Bias = (const float*)d_in[2];
    float* Out        = (float*)d_out;
    const size_t wsneed = (size_t)NB * WIMG;   // 5,734,400 B
    if (ws_size >= wsneed) {
        wconv_kernel<<<(NB * WROWS * 16 + 255) / 256, 256, 0, stream>>>(W, (unsigned char*)d_ws);
        mtl_heads_runs<<<dim3(NBLK), 256, 0, stream>>>(X, Bias, (const unsigned char*)d_ws, Out);
    } else {
        mtl_heads_fallback<<<dim3(16, NB), 256, 0, stream>>>(X, W, Bias, Out);
    }
}

// Round 17
// 71.923 us; speedup vs baseline: 3.2527x; 1.0075x over previous
//
#include <hip/hip_runtime.h>
#include <hip/hip_bf16.h>

// Problem constants (reference: B=2048, N_BINS=200, D=128, G=100)
#define NB    200
#define BSZ   2048
#define DD    128
#define GG    100
#define WROWS 112                 // gene rows padded in the d_ws image
#define ROWB  256                 // bytes per LDS W row (128 bf16)
#define WIMG  (WROWS * ROWB)      // 28672 B per-bin W image in d_ws
#define WLDS  (GG * ROWB)         // 25600 B staged per W buffer (100 real rows)
#define SCR   6400                // per-wave dedicated epilogue scratch
#define NTILE (NB * 16)           // 3200 (tile = n*16 + mtile)
#define NBLK  512                 // grid size (2 blocks/CU)

typedef __attribute__((ext_vector_type(8))) short  short8;  // 8 bf16 (MFMA A/B frag)
typedef __attribute__((ext_vector_type(4))) float  f32x4;   // MFMA C/D frag
typedef __attribute__((ext_vector_type(4))) int    i32x4;   // 16B chunk

// round-to-nearest-even f32 -> bf16, two at a time packed into a dword
__device__ __forceinline__ unsigned f2bf_pack(float lo, float hi) {
    unsigned ulo = __builtin_bit_cast(unsigned, lo);
    ulo += 0x7FFFu + ((ulo >> 16) & 1u);
    unsigned uhi = __builtin_bit_cast(unsigned, hi);
    uhi += 0x7FFFu + ((uhi >> 16) & 1u);
    return (ulo >> 16) | (uhi & 0xFFFF0000u);
}

__device__ __forceinline__ void gload_lds16(const void* g, void* l) {
    __builtin_amdgcn_global_load_lds(
        (const __attribute__((address_space(1))) unsigned int*)g,
        (__attribute__((address_space(3))) unsigned int*)l, 16, 0, 0);
}

// Wave-level LDS drain (scratch is wave-private): lgkmcnt(0) only.
#define WAIT_LGKM0() do { asm volatile("" ::: "memory");     \
                          __builtin_amdgcn_s_waitcnt(0xC07F);\
                          __builtin_amdgcn_sched_barrier(0); \
                          __builtin_amdgcn_wave_barrier();   \
                          asm volatile("" ::: "memory"); } while (0)

// Bin-change barrier: drain own staging (older than the 14 newest NT
// stores; vmcnt retires in order), then sync waves -> all staging chunks
// of the NEXT W buffer have landed before any wave reads it.
#define BARRIER_STAGE() do { asm volatile("s_waitcnt vmcnt(14)" ::: "memory"); \
                             __builtin_amdgcn_s_barrier();        \
                             __builtin_amdgcn_sched_barrier(0);   \
                             asm volatile("" ::: "memory"); } while (0)

// Prologue barrier: full drain.
#define BARRIER_VM0() do { asm volatile("s_waitcnt vmcnt(0) lgkmcnt(0)" ::: "memory"); \
                           __builtin_amdgcn_s_barrier();        \
                           __builtin_amdgcn_sched_barrier(0);   \
                           asm volatile("" ::: "memory"); } while (0)

// NOTES (r11-r16 lessons):
//  - __launch_bounds__(256,2) only: (256,3) triggers a register-allocator
//    heuristic that spills the X prefetch (VGPR 84, +250 MB traffic).
//  - Grid 512 + 64-tile XCD chunks: grid 768 regressed (residency/L2).
//  - r17 change: DEDICATED epilogue scratch (W dbuf 51.2K + scratch 25.6K =
//    76.8K, still 2 blocks/CU) -> scratch never aliases W -> the 2-per-tile
//    cross-wave barriers of r16 are GONE. Only prologue + <=1 bin-change
//    barrier per block remain; waves drift independently across the run.

// ---------------------------------------------------------------------------
// Pre-pass: W f32 [NB][GG][DD] -> bf16 swizzled per-bin images in d_ws.
// byte off = row*256 + ((granule*16) ^ ((row&7)<<4)), rows >= GG zeroed.
// ---------------------------------------------------------------------------
__global__ __launch_bounds__(256) void wconv_kernel(
    const float* __restrict__ W, unsigned char* __restrict__ ws)
{
    const int gidx = blockIdx.x * 256 + threadIdx.x;
    if (gidx >= NB * WROWS * 16) return;
    const int gr  = gidx & 15;
    const int row = (gidx >> 4) % WROWS;
    const int n   = gidx / (WROWS * 16);
    i32x4 pack = (i32x4){0, 0, 0, 0};
    if (row < GG) {
        const float* src = W + ((size_t)n * GG + row) * DD + gr * 8;
        const f32x4 a = *reinterpret_cast<const f32x4*>(src);
        const f32x4 b = *reinterpret_cast<const f32x4*>(src + 4);
        pack.x = (int)f2bf_pack(a[0], a[1]);
        pack.y = (int)f2bf_pack(a[2], a[3]);
        pack.z = (int)f2bf_pack(b[0], b[1]);
        pack.w = (int)f2bf_pack(b[2], b[3]);
    }
    const int off = row * ROWB + ((gr * 16) ^ ((row & 7) << 4));
    *reinterpret_cast<i32x4*>(ws + (size_t)n * WIMG + off) = pack;
}

// ---------------------------------------------------------------------------
// Helpers
// ---------------------------------------------------------------------------
// Stage the 100 real rows (25600 B) of bin n's image: 25 wave-chunks of 1024 B.
__device__ __forceinline__ void stage_tile(char* buf, const unsigned char* WS,
                                           int n, int lane, int wid) {
    const unsigned char* src = WS + (size_t)n * WIMG;
    #pragma unroll
    for (int i = 0; i < 6; ++i) {
        const int c = i * 4 + wid;                    // chunks 0..23
        gload_lds16(src + c * 1024 + lane * 16, buf + c * 1024);
    }
    if (wid == 0)                                     // chunk 24 (rows 96..99)
        gload_lds16(src + 24 * 1024 + lane * 16, buf + 24 * 1024);
}

__device__ __forceinline__ void load_x(f32x4 (&raw)[2][4][2], const float* X,
                                       int tile, int wid, int l15, int lhi) {
    const int n = tile >> 4;
    const int rowbase = (tile & 15) * 128 + wid * 32;
    #pragma unroll
    for (int rf = 0; rf < 2; ++rf) {
        const float* xrow = X + ((size_t)(rowbase + rf * 16 + l15) * NB + n) * DD + lhi * 8;
        #pragma unroll
        for (int ks = 0; ks < 4; ++ks) {
            raw[rf][ks][0] = *reinterpret_cast<const f32x4*>(xrow + ks * 32);
            raw[rf][ks][1] = *reinterpret_cast<const f32x4*>(xrow + ks * 32 + 4);
        }
    }
}

__device__ __forceinline__ void conv_x(const f32x4 (&raw)[2][4][2],
                                       short8 (&areg)[2][4]) {
    #pragma unroll
    for (int rf = 0; rf < 2; ++rf)
        #pragma unroll
        for (int ks = 0; ks < 4; ++ks) {
            const f32x4 a = raw[rf][ks][0];
            const f32x4 b = raw[rf][ks][1];
            i32x4 pk;
            pk.x = (int)f2bf_pack(a[0], a[1]);
            pk.y = (int)f2bf_pack(a[2], a[3]);
            pk.z = (int)f2bf_pack(b[0], b[1]);
            pk.w = (int)f2bf_pack(b[2], b[3]);
            areg[rf][ks] = __builtin_bit_cast(short8, pk);
        }
}

// ---------------------------------------------------------------------------
// Barrier-free-run main kernel: each block owns 6-7 CONSECUTIVE tiles (<=1
// bin boundary). W double-buffered in LDS; epilogue uses a DEDICATED scratch
// region -> no per-tile cross-wave barriers. Waves drift independently; the
// only s_barriers are the prologue and the (<=1) bin-change staging fence.
// LDS = 2*25600 (W) + 4*6400 (scratch) = 76800 B -> 2 blocks/CU.
// ---------------------------------------------------------------------------
__global__ __launch_bounds__(256, 2) void mtl_heads_free(
    const float* __restrict__ X, const float* __restrict__ Bias,
    const unsigned char* __restrict__ WS, float* __restrict__ Out)
{
    const int tid  = threadIdx.x;
    const int lane = tid & 63;
    const int wid  = tid >> 6;
    const int l15  = lane & 15;
    const int lhi  = lane >> 4;

    __shared__ __align__(16) char smem[2 * WLDS + 4 * SCR];   // 76800 B
    char* wbuf = smem;                  // current bin's W
    char* obuf = smem + WLDS;           // next bin's W (staged on bin change)
    char* scratch = smem + 2 * WLDS + wid * SCR;   // dedicated, never aliases W

    // XCD swizzle (r12-proven): s consecutive within an XCD. Heavy (7-tile)
    // blocks every 4th s: start(s) = 6s + ceil(s/4), cnt = (s%4==0)?7:6.
    const int s   = ((blockIdx.x & 7) << 6) + (blockIdx.x >> 3);
    const int cnt = ((s & 3) == 0) ? 7 : 6;
    int t = 6 * s + ((s + 3) >> 2);

    // prologue: stage W(bin(t)) + first X tile, full drain, convert
    stage_tile(wbuf, WS, t >> 4, lane, wid);
    f32x4 raw[2][4][2];
    load_x(raw, X, t, wid, l15, lhi);
    BARRIER_VM0();
    short8 areg[2][4];
    conv_x(raw, areg);

    for (int i = 0; i < cnt; ++i, ++t) {
        const int  n       = t >> 4;
        const int  rowbase = (t & 15) * 128 + wid * 32;
        const bool hasnext = (i + 1 < cnt);
        const bool binchg  = hasnext && (((t + 1) & 15) == 0);

        // 1. prefetch: W into the OTHER buffer on bin change; X always
        if (binchg)  stage_tile(obuf, WS, (t + 1) >> 4, lane, wid);
        if (hasnext) load_x(raw, X, t + 1, wid, l15, lhi);
        float bias[7];
        #pragma unroll
        for (int cf = 0; cf < 7; ++cf) {
            const int g = cf * 16 + l15;
            bias[cf] = (g < GG) ? Bias[n * GG + g] : 0.0f;
        }

        // 2. MFMA: 2 row-frags x 7 col-frags x 4 k-steps from wbuf
        f32x4 acc[2][7];
        #pragma unroll
        for (int rf = 0; rf < 2; ++rf)
            #pragma unroll
            for (int cf = 0; cf < 7; ++cf)
                acc[rf][cf] = (f32x4){0.f, 0.f, 0.f, 0.f};

        #pragma unroll
        for (int cf = 0; cf < 7; ++cf) {
            const int g    = cf * 16 + l15;          // B-frag: gene row of W
            const int rowb = g * ROWB;
            const int swz  = (g & 7) << 4;
            #pragma unroll
            for (int ks = 0; ks < 4; ++ks) {
                const int off = rowb + (((lhi * 16) + ks * 64) ^ swz);
                const i32x4 braw = *reinterpret_cast<const i32x4*>(wbuf + off);  // ds_read_b128
                const short8 bfrag = __builtin_bit_cast(short8, braw);
                acc[0][cf] = __builtin_amdgcn_mfma_f32_16x16x32_bf16(areg[0][ks], bfrag, acc[0][cf], 0, 0, 0);
                acc[1][cf] = __builtin_amdgcn_mfma_f32_16x16x32_bf16(areg[1][ks], bfrag, acc[1][cf], 0, 0, 0);
            }
        }

        // 3. epilogue via dedicated scratch: wave-private sync ONLY — no
        //    cross-wave barrier (scratch never aliases W; W is read-only
        //    for the whole bin; staging targets the other buffer).
        #pragma unroll
        for (int rf = 0; rf < 2; ++rf) {
            float* lds_f = reinterpret_cast<float*>(scratch);
            #pragma unroll
            for (int cf = 0; cf < 7; ++cf) {
                const int g = cf * 16 + l15;
                if (g < GG) {
                    #pragma unroll
                    for (int j = 0; j < 4; ++j)
                        lds_f[(lhi * 4 + j) * GG + g] = acc[rf][cf][j] + bias[cf];
                }
            }
            WAIT_LGKM0();
            char* dst = (char*)(Out + ((size_t)n * BSZ + rowbase + rf * 16) * GG);
            #pragma unroll
            for (int it = 0; it < 7; ++it) {
                const int c = it * 64 + lane;         // 16B-chunk index, 400 total
                if (c < 400) {
                    const i32x4 v = *reinterpret_cast<const i32x4*>(scratch + c * 16);
                    __builtin_nontemporal_store(v, reinterpret_cast<i32x4*>(dst + c * 16));
                }
            }
            WAIT_LGKM0();   // scratch reads done before rf=1 / next tile overwrites
        }

        // 4. convert next tile's X (compiler inserts counted vmcnt for raw)
        if (hasnext) conv_x(raw, areg);

        // 5. bin-change fence only: all waves' staging landed in obuf
        //    (vmcnt(14): staging is older than this tile's 14 NT stores).
        if (binchg) {
            BARRIER_STAGE();
            char* tmp = wbuf; wbuf = obuf; obuf = tmp;
        }
    }
}

// ---------------------------------------------------------------------------
// Fallback (no workspace): single-tile kernel, in-kernel W convert.
// ---------------------------------------------------------------------------
__global__ __launch_bounds__(256, 4) void mtl_heads_fallback(
    const float* __restrict__ X, const float* __restrict__ W,
    const float* __restrict__ Bias, float* __restrict__ Out)
{
    const int n     = blockIdx.y;
    const int mtile = blockIdx.x;
    const int tid   = threadIdx.x;
    const int lane  = tid & 63;
    const int wid   = tid >> 6;
    const int l15   = lane & 15;
    const int lhi   = lane >> 4;

    __shared__ __align__(16) char smem[WIMG];

    {
        const int rsub = tid >> 4;
        const int k0   = (tid & 15) * 8;
        #pragma unroll
        for (int it = 0; it < 7; ++it) {
            const int row = it * 16 + rsub;
            i32x4 pack = (i32x4){0, 0, 0, 0};
            if (row < GG) {
                const float* sp = W + ((size_t)n * GG + row) * DD + k0;
                const f32x4 a = *reinterpret_cast<const f32x4*>(sp);
                const f32x4 b = *reinterpret_cast<const f32x4*>(sp + 4);
                pack.x = (int)f2bf_pack(a[0], a[1]);
                pack.y = (int)f2bf_pack(a[2], a[3]);
                pack.z = (int)f2bf_pack(b[0], b[1]);
                pack.w = (int)f2bf_pack(b[2], b[3]);
            }
            const int off = row * ROWB + ((k0 * 2) ^ ((row & 7) << 4));
            *reinterpret_cast<i32x4*>(smem + off) = pack;
        }
    }

    const int rowbase = mtile * 128 + wid * 32;
    f32x4 raw[2][4][2];
    load_x(raw, X, n * 16 + mtile, wid, l15, lhi);
    float bias[7];
    #pragma unroll
    for (int cf = 0; cf < 7; ++cf) {
        const int g = cf * 16 + l15;
        bias[cf] = (g < GG) ? Bias[n * GG + g] : 0.0f;
    }
    short8 areg[2][4];
    conv_x(raw, areg);

    __syncthreads();

    f32x4 acc[2][7];
    #pragma unroll
    for (int rf = 0; rf < 2; ++rf)
        #pragma unroll
        for (int cf = 0; cf < 7; ++cf)
            acc[rf][cf] = (f32x4){0.f, 0.f, 0.f, 0.f};

    #pragma unroll
    for (int cf = 0; cf < 7; ++cf) {
        const int g    = cf * 16 + l15;
        const int rowb = g * ROWB;
        const int swz  = (g & 7) << 4;
        #pragma unroll
        for (int ks = 0; ks < 4; ++ks) {
            const int off = rowb + (((lhi * 16) + ks * 64) ^ swz);
            const i32x4 braw = *reinterpret_cast<const i32x4*>(smem + off);
            const short8 bfrag = __builtin_bit_cast(short8, braw);
            acc[0][cf] = __builtin_amdgcn_mfma_f32_16x16x32_bf16(areg[0][ks], bfrag, acc[0][cf], 0, 0, 0);
            acc[1][cf] = __builtin_amdgcn_mfma_f32_16x16x32_bf16(areg[1][ks], bfrag, acc[1][cf], 0, 0, 0);
        }
    }

    __syncthreads();

    float* lds_f = reinterpret_cast<float*>(smem + wid * SCR);
    #pragma unroll
    for (int rf = 0; rf < 2; ++rf) {
        #pragma unroll
        for (int cf = 0; cf < 7; ++cf) {
            const int g = cf * 16 + l15;
            if (g < GG) {
                #pragma unroll
                for (int j = 0; j < 4; ++j)
                    lds_f[(lhi * 4 + j) * GG + g] = acc[rf][cf][j] + bias[cf];
            }
        }
        WAIT_LGKM0();
        const char* rgn = smem + wid * SCR;
        char* dst = (char*)(Out + ((size_t)n * BSZ + rowbase + rf * 16) * GG);
        #pragma unroll
        for (int it = 0; it < 7; ++it) {
            const int c = it * 64 + lane;
            if (c < 400) {
                const i32x4 v = *reinterpret_cast<const i32x4*>(rgn + c * 16);
                *reinterpret_cast<i32x4*>(dst + c * 16) = v;
            }
        }
        WAIT_LGKM0();
    }
}

extern "C" void kernel_launch(void* const* d_in, const int* in_sizes, int n_in,
                              void* d_out, int out_size, void* d_ws, size_t ws_size,
                              hipStream_t stream) {
    (void)in_sizes; (void)n_in; (void)out_size;
    const float* X    = (const float*)d_in[0];
    const float* W    = (const float*)d_in[1];
    const float* Bias = (const float*)d_in[2];
    float* Out        = (float*)d_out;
    const size_t wsneed = (size_t)NB * WIMG;   // 5,734,400 B
    if (ws_size >= wsneed) {
        wconv_kernel<<<(NB * WROWS * 16 + 255) / 256, 256, 0, stream>>>(W, (unsigned char*)d_ws);
        mtl_heads_free<<<dim3(NBLK), 256, 0, stream>>>(X, Bias, (const unsigned char*)d_ws, Out);
    } else {
        mtl_heads_fallback<<<dim3(16, NB), 256, 0, stream>>>(X, W, Bias, Out);
    }
}